// Round 2
// baseline (351.666 us; speedup 1.0000x reference)
//
#include <hip/hip_runtime.h>

typedef _Float16 f16;
typedef __attribute__((ext_vector_type(8))) _Float16 f16x8;
typedef __attribute__((ext_vector_type(4))) _Float16 f16x4;
typedef __attribute__((ext_vector_type(4))) float f32x4;

#define S_LEN 2048
#define NB 8
#define NH 4
#define DM 128
#define DK 32

static __device__ __forceinline__ f32x4 mfma_16x16x32(f16x8 a, f16x8 b, f32x4 c) {
  return __builtin_amdgcn_mfma_f32_16x16x32_f16(a, b, c, 0, 0, 0);
}

// ---------------------------------------------------------------------------
// Kernel 1: fused q/k/v projections.
//   mode 0: qh[bh][s][dk] = (Q@wq + bq) * (1/sqrt(32))   (fp16)
//   mode 1: kh[bh][s][dk] = (K@wk + bk)                  (fp16)
//   mode 2: vt[bh][dk][s] = (V@wv + bv) transposed       (fp16)
// ---------------------------------------------------------------------------
__global__ __launch_bounds__(256) void proj_kernel(
    const float* __restrict__ Qx, const float* __restrict__ Kx, const float* __restrict__ Vx,
    const float* __restrict__ wq, const float* __restrict__ bq,
    const float* __restrict__ wk, const float* __restrict__ bk,
    const float* __restrict__ wv, const float* __restrict__ bv,
    f16* __restrict__ qh, f16* __restrict__ kh, f16* __restrict__ vt)
{
  const int mode = blockIdx.y;
  const float* X = (mode == 0) ? Qx : (mode == 1) ? Kx : Vx;
  const float* W = (mode == 0) ? wq : (mode == 1) ? wk : wv;
  const float* Bp = (mode == 0) ? bq : (mode == 1) ? bk : bv;

  __shared__ float xt[16][128];
  const int t = threadIdx.x;
  const int row0 = blockIdx.x * 16;  // 16 token rows per block

  const f32x4* src = (const f32x4*)(X + (size_t)row0 * DM);
  f32x4* dst4 = (f32x4*)(&xt[0][0]);
  dst4[t] = src[t];
  dst4[t + 256] = src[t + 256];
  __syncthreads();

  const int j = t & 127;   // output column
  const int rg = t >> 7;   // row group (0/1), 8 rows each
  float acc[8];
#pragma unroll
  for (int r = 0; r < 8; ++r) acc[r] = 0.f;
  for (int k = 0; k < 128; ++k) {
    float wkj = W[k * 128 + j];
#pragma unroll
    for (int r = 0; r < 8; ++r) acc[r] += xt[rg * 8 + r][k] * wkj;
  }
  const float bb = Bp[j];
  const int hh = j >> 5, dd = j & 31;

  if (mode < 2) {
    const float scale = (mode == 0) ? 0.17677669529663687f : 1.0f;  // 1/sqrt(32)
    f16* outp = (mode == 0) ? qh : kh;
#pragma unroll
    for (int r = 0; r < 8; ++r) {
      int row = row0 + rg * 8 + r;
      int b = row >> 11, s = row & (S_LEN - 1);
      outp[((size_t)(b * NH + hh) * S_LEN + s) * DK + dd] = (f16)((acc[r] + bb) * scale);
    }
  } else {
    int b = row0 >> 11, s0 = row0 & (S_LEN - 1);
    f16x8 v8;
#pragma unroll
    for (int r = 0; r < 8; ++r) v8[r] = (f16)(acc[r] + bb);
    f16* dst = vt + ((size_t)(b * NH + hh) * DK + dd) * S_LEN + s0 + rg * 8;
    *(f16x8*)dst = v8;
  }
}

// ---------------------------------------------------------------------------
// Kernel 2: attention, kv-split for occupancy.
// Block = 4 waves = 2 q-tiles (16 rows each) x 2 kv-halves (1024 kv each).
// Grid = 32 bh * 64 tile-pairs = 2048 blocks -> 8 blocks/CU, 32 waves/CU cap.
// Swapped QK^T: lane owns q = lane&15; softmax partial sums and partial PV
// combine across the two kv-half waves via LDS.
// ---------------------------------------------------------------------------
__global__ __launch_bounds__(256, 8) void attn_kernel(
    const f16* __restrict__ qh, const f16* __restrict__ kh, const f16* __restrict__ vt,
    const unsigned char* __restrict__ mask,
    float* __restrict__ attn, float* __restrict__ ctx)
{
  const int bx = blockIdx.x;
  const int bh = bx >> 6;              // 0..31  (b*4+h)
  const int qp = bx & 63;              // 32-row pair index
  const int wave = threadIdx.x >> 6;
  const int tile = wave >> 1;          // which 16-row tile
  const int half = wave & 1;           // which kv half
  const int lane = threadIdx.x & 63;
  const int ln = lane & 15, hi = lane >> 4;
  const int b = bh >> 2, h = bh & 3;
  const int qrow = qp * 32 + tile * 16 + ln;
  const int kv0 = half * (S_LEN / 2);
  const int kv1 = kv0 + (S_LEN / 2);

  __shared__ float sums[2][2][16];
  __shared__ float ctxbuf[2][16][32];

  const f16* kbase = kh + (size_t)bh * S_LEN * DK;
  const f16* vbase = vt + (size_t)bh * DK * S_LEN;
  const unsigned char* mrow = mask + ((size_t)b * S_LEN + qrow) * S_LEN;

  const f16x8 qfrag = *(const f16x8*)(qh + ((size_t)bh * S_LEN + qrow) * DK + hi * 8);
  const f32x4 zero = {0.f, 0.f, 0.f, 0.f};

  // ---- pass 1: partial row sums of exp(scores), 64 kv per iter ----
  float sum = 0.f;
  for (int kv = kv0; kv < kv1; kv += 64) {
    f16x8 k0 = *(const f16x8*)(kbase + (size_t)(kv + ln) * DK + hi * 8);
    f16x8 k1 = *(const f16x8*)(kbase + (size_t)(kv + 16 + ln) * DK + hi * 8);
    f16x8 k2 = *(const f16x8*)(kbase + (size_t)(kv + 32 + ln) * DK + hi * 8);
    f16x8 k3 = *(const f16x8*)(kbase + (size_t)(kv + 48 + ln) * DK + hi * 8);
    uchar4 m0 = *(const uchar4*)(mrow + kv + hi * 4);
    uchar4 m1 = *(const uchar4*)(mrow + kv + 16 + hi * 4);
    uchar4 m2 = *(const uchar4*)(mrow + kv + 32 + hi * 4);
    uchar4 m3 = *(const uchar4*)(mrow + kv + 48 + hi * 4);
    f32x4 s0 = mfma_16x16x32(k0, qfrag, zero);
    f32x4 s1 = mfma_16x16x32(k1, qfrag, zero);
    f32x4 s2 = mfma_16x16x32(k2, qfrag, zero);
    f32x4 s3 = mfma_16x16x32(k3, qfrag, zero);
#pragma unroll
    for (int r = 0; r < 4; ++r) {
      float e0 = (&m0.x)[r] ? 0.f : __expf(s0[r]);
      float e1 = (&m1.x)[r] ? 0.f : __expf(s1[r]);
      float e2 = (&m2.x)[r] ? 0.f : __expf(s2[r]);
      float e3 = (&m3.x)[r] ? 0.f : __expf(s3[r]);
      sum += (e0 + e1) + (e2 + e3);
    }
  }
  sum += __shfl_xor(sum, 16);
  sum += __shfl_xor(sum, 32);
  if (lane < 16) sums[tile][half][ln] = sum;
  __syncthreads();
  const float inv = 1.f / (sums[tile][0][ln] + sums[tile][1][ln]);

  // ---- pass 2: recompute, write normalized attn, accumulate partial PV ----
  f32x4 c0 = zero, c1 = zero;
  float* arow = attn + ((size_t)bh * S_LEN + qrow) * S_LEN;
  for (int kv = kv0; kv < kv1; kv += 32) {
    f16x8 k0 = *(const f16x8*)(kbase + (size_t)(kv + ln) * DK + hi * 8);
    f16x8 k1 = *(const f16x8*)(kbase + (size_t)(kv + 16 + ln) * DK + hi * 8);
    uchar4 m0 = *(const uchar4*)(mrow + kv + hi * 4);
    uchar4 m1 = *(const uchar4*)(mrow + kv + 16 + hi * 4);
    const f16* v0p = vbase + (size_t)ln * S_LEN + kv + hi * 4;         // dv = ln
    const f16* v1p = vbase + (size_t)(16 + ln) * S_LEN + kv + hi * 4;  // dv = 16+ln
    f16x4 va0 = *(const f16x4*)v0p;
    f16x4 va1 = *(const f16x4*)(v0p + 16);
    f16x4 vb0 = *(const f16x4*)v1p;
    f16x4 vb1 = *(const f16x4*)(v1p + 16);
    f32x4 s0 = mfma_16x16x32(k0, qfrag, zero);
    f32x4 s1 = mfma_16x16x32(k1, qfrag, zero);
    f32x4 p0, p1;
#pragma unroll
    for (int r = 0; r < 4; ++r) {
      p0[r] = (&m0.x)[r] ? 0.f : __expf(s0[r]) * inv;
      p1[r] = (&m1.x)[r] ? 0.f : __expf(s1[r]) * inv;
    }
    __builtin_nontemporal_store(p0, (f32x4*)(arow + kv + hi * 4));
    __builtin_nontemporal_store(p1, (f32x4*)(arow + kv + 16 + hi * 4));

    f16x8 pf;
#pragma unroll
    for (int r = 0; r < 4; ++r) { pf[r] = (f16)p0[r]; pf[r + 4] = (f16)p1[r]; }

    f16x8 vf0 = __builtin_shufflevector(va0, va1, 0, 1, 2, 3, 4, 5, 6, 7);
    f16x8 vf1 = __builtin_shufflevector(vb0, vb1, 0, 1, 2, 3, 4, 5, 6, 7);
    c0 = mfma_16x16x32(vf0, pf, c0);
    c1 = mfma_16x16x32(vf1, pf, c1);
  }

  // combine the two kv-half partial PVs via LDS
  if (half == 1) {
#pragma unroll
    for (int r = 0; r < 4; ++r) {
      ctxbuf[tile][ln][hi * 4 + r] = c0[r];
      ctxbuf[tile][ln][16 + hi * 4 + r] = c1[r];
    }
  }
  __syncthreads();
  if (half == 0) {
#pragma unroll
    for (int r = 0; r < 4; ++r) {
      c0[r] += ctxbuf[tile][ln][hi * 4 + r];
      c1[r] += ctxbuf[tile][ln][16 + hi * 4 + r];
    }
    float* crow = ctx + ((size_t)b * S_LEN + qrow) * DM + h * DK;
    *(f32x4*)(crow + hi * 4) = c0;
    *(f32x4*)(crow + 16 + hi * 4) = c1;
  }
}

// ---------------------------------------------------------------------------
// Kernel 3: out = LayerNorm(ctx @ wo + bo + residual(Q)) * gamma + beta
// ---------------------------------------------------------------------------
__global__ __launch_bounds__(256) void out_ln_kernel(
    const float* __restrict__ ctx, const float* __restrict__ Qin,
    const float* __restrict__ wo, const float* __restrict__ bo,
    const float* __restrict__ gamma, const float* __restrict__ beta,
    float* __restrict__ out)
{
  __shared__ float xt[16][128];
  __shared__ float yt[16][128];
  const int t = threadIdx.x;
  const int row0 = blockIdx.x * 16;

  const f32x4* src = (const f32x4*)(ctx + (size_t)row0 * DM);
  f32x4* dst4 = (f32x4*)(&xt[0][0]);
  dst4[t] = src[t];
  dst4[t + 256] = src[t + 256];
  __syncthreads();

  const int j = t & 127;
  const int rg = t >> 7;
  float acc[8];
#pragma unroll
  for (int r = 0; r < 8; ++r) acc[r] = 0.f;
  for (int k = 0; k < 128; ++k) {
    float wkj = wo[k * 128 + j];
#pragma unroll
    for (int r = 0; r < 8; ++r) acc[r] += xt[rg * 8 + r][k] * wkj;
  }
  const float bb = bo[j];
#pragma unroll
  for (int r = 0; r < 8; ++r) {
    int row = row0 + rg * 8 + r;
    yt[rg * 8 + r][j] = acc[r] + bb + Qin[(size_t)row * DM + j];
  }
  __syncthreads();

  const int wv = t >> 6, lnid = t & 63;
#pragma unroll
  for (int r = 0; r < 4; ++r) {
    int row = wv * 4 + r;
    float a = yt[row][lnid];
    float b2 = yt[row][lnid + 64];
    float s = a + b2, sq = a * a + b2 * b2;
#pragma unroll
    for (int off = 32; off >= 1; off >>= 1) {
      s += __shfl_xor(s, off);
      sq += __shfl_xor(sq, off);
    }
    float mu = s * (1.f / 128.f);
    float var = sq * (1.f / 128.f) - mu * mu;
    float rstd = rsqrtf(var + 1e-5f);
    size_t orow = (size_t)(row0 + row) * DM;
    out[orow + lnid] = (a - mu) * rstd * gamma[lnid] + beta[lnid];
    out[orow + lnid + 64] = (b2 - mu) * rstd * gamma[lnid + 64] + beta[lnid + 64];
  }
}

// ---------------------------------------------------------------------------
extern "C" void kernel_launch(void* const* d_in, const int* in_sizes, int n_in,
                              void* d_out, int out_size, void* d_ws, size_t ws_size,
                              hipStream_t stream) {
  const float* Q    = (const float*)d_in[0];
  const float* K    = (const float*)d_in[1];
  const float* V    = (const float*)d_in[2];
  const unsigned char* mask = (const unsigned char*)d_in[3];
  const float* wq   = (const float*)d_in[4];
  const float* bq   = (const float*)d_in[5];
  const float* wk   = (const float*)d_in[6];
  const float* bk   = (const float*)d_in[7];
  const float* wv   = (const float*)d_in[8];
  const float* bv   = (const float*)d_in[9];
  const float* wo   = (const float*)d_in[10];
  const float* bo   = (const float*)d_in[11];
  const float* gamma= (const float*)d_in[12];
  const float* beta = (const float*)d_in[13];

  const size_t HEAD_ELEMS = (size_t)NB * NH * S_LEN * DK;  // 2,097,152

  f16* qh = (f16*)d_ws;
  f16* kh = qh + HEAD_ELEMS;
  f16* vt = kh + HEAD_ELEMS;
  float* ctx = (float*)(vt + HEAD_ELEMS);  // 8 MB fp32, 16B-aligned

  float* out  = (float*)d_out;                       // [8,2048,128]
  float* attn = out + (size_t)NB * S_LEN * DM;       // [8,4,2048,2048]

  proj_kernel<<<dim3(1024, 3), 256, 0, stream>>>(Q, K, V, wq, bq, wk, bk, wv, bv, qh, kh, vt);
  attn_kernel<<<2048, 256, 0, stream>>>(qh, kh, vt, mask, attn, ctx);
  out_ln_kernel<<<1024, 256, 0, stream>>>(ctx, Q, wo, bo, gamma, beta, out);
}

// Round 3
// 331.686 us; speedup vs baseline: 1.0602x; 1.0602x over previous
//
#include <hip/hip_runtime.h>

typedef _Float16 f16;
typedef __attribute__((ext_vector_type(8))) _Float16 f16x8;
typedef __attribute__((ext_vector_type(4))) _Float16 f16x4;
typedef __attribute__((ext_vector_type(4))) float f32x4;
typedef unsigned int u32;
typedef __attribute__((ext_vector_type(2))) unsigned int u32x2;
typedef __attribute__((ext_vector_type(4))) unsigned int u32x4;

#define S_LEN 2048
#define NB 8
#define NH 4
#define DM 128
#define DK 32

static __device__ __forceinline__ f32x4 mfma_16x16x32(f16x8 a, f16x8 b, f32x4 c) {
  return __builtin_amdgcn_mfma_f32_16x16x32_f16(a, b, c, 0, 0, 0);
}

// ---------------------------------------------------------------------------
// Kernel 0: pack bool mask (uint8) into bit-words. word w bit j = mask[32w+j].
// Thread t loads 16 contiguous bytes; lane pairs combine via shfl.
// ---------------------------------------------------------------------------
__global__ __launch_bounds__(256) void pack_mask_kernel(
    const unsigned char* __restrict__ mask, u32* __restrict__ words)
{
  const int tid = blockIdx.x * 256 + threadIdx.x;
  u32x4 v = *(const u32x4*)(mask + (size_t)tid * 16);
  u32 bits = 0;
#pragma unroll
  for (int i = 0; i < 4; ++i) {
    u32 u = v[i];
#pragma unroll
    for (int k = 0; k < 4; ++k)
      bits |= (((u >> (8 * k)) & 0xffu) ? 1u : 0u) << (4 * i + k);
  }
  u32 other = __shfl_xor(bits, 1);
  if ((threadIdx.x & 1) == 0) words[tid >> 1] = bits | (other << 16);
}

// ---------------------------------------------------------------------------
// Kernel 1: fused q/k/v projections.
//   mode 0: qh[bh][s][dk] = (Q@wq + bq) * (1/sqrt(32))   (fp16)
//   mode 1: kh[bh][s][dk] = (K@wk + bk)                  (fp16)
//   mode 2: vt swizzled tiles: per bh, 32-kv tile t, layout [dv(32)][hi(4)][8]
//           where the 8 f16 for (dv,hi) are kv = t*32 + {4hi+r, 16+4hi+r}.
//           This makes the PV A-fragment a single contiguous 1KB wave-load.
// ---------------------------------------------------------------------------
__global__ __launch_bounds__(256) void proj_kernel(
    const float* __restrict__ Qx, const float* __restrict__ Kx, const float* __restrict__ Vx,
    const float* __restrict__ wq, const float* __restrict__ bq,
    const float* __restrict__ wk, const float* __restrict__ bk,
    const float* __restrict__ wv, const float* __restrict__ bv,
    f16* __restrict__ qh, f16* __restrict__ kh, f16* __restrict__ vt)
{
  const int mode = blockIdx.y;
  const float* X = (mode == 0) ? Qx : (mode == 1) ? Kx : Vx;
  const float* W = (mode == 0) ? wq : (mode == 1) ? wk : wv;
  const float* Bp = (mode == 0) ? bq : (mode == 1) ? bk : bv;

  __shared__ float xt[16][128];
  const int t = threadIdx.x;
  const int row0 = blockIdx.x * 16;

  const f32x4* src = (const f32x4*)(X + (size_t)row0 * DM);
  f32x4* dst4 = (f32x4*)(&xt[0][0]);
  dst4[t] = src[t];
  dst4[t + 256] = src[t + 256];
  __syncthreads();

  const int j = t & 127;
  const int rg = t >> 7;
  float acc[8];
#pragma unroll
  for (int r = 0; r < 8; ++r) acc[r] = 0.f;
  for (int k = 0; k < 128; ++k) {
    float wkj = W[k * 128 + j];
#pragma unroll
    for (int r = 0; r < 8; ++r) acc[r] += xt[rg * 8 + r][k] * wkj;
  }
  const float bb = Bp[j];
  const int hh = j >> 5, dd = j & 31;

  if (mode < 2) {
    const float scale = (mode == 0) ? 0.17677669529663687f : 1.0f;  // 1/sqrt(32)
    f16* outp = (mode == 0) ? qh : kh;
#pragma unroll
    for (int r = 0; r < 8; ++r) {
      int row = row0 + rg * 8 + r;
      int b = row >> 11, s = row & (S_LEN - 1);
      outp[((size_t)(b * NH + hh) * S_LEN + s) * DK + dd] = (f16)((acc[r] + bb) * scale);
    }
  } else {
    int b = row0 >> 11;
    int sA = (row0 & (S_LEN - 1)) + rg * 8;   // 8 consecutive s, same 32-tile
    f16* base = vt + (size_t)(b * NH + hh) * DK * S_LEN;
    int t4 = sA >> 5;
    int u0 = sA & 31;                 // 0,8,16,24
    int half = u0 >> 4;
    int hi4 = (u0 >> 2) & 3;          // r<4 -> hi4 ; r>=4 -> hi4+1
    f16* p = base + (size_t)t4 * 1024 + dd * 32 + half * 4;
    f16x4 lo, hi8;
#pragma unroll
    for (int r = 0; r < 4; ++r) lo[r] = (f16)(acc[r] + bb);
#pragma unroll
    for (int r = 0; r < 4; ++r) hi8[r] = (f16)(acc[r + 4] + bb);
    *(f16x4*)(p + hi4 * 8) = lo;
    *(f16x4*)(p + (hi4 + 1) * 8) = hi8;
  }
}

// ---------------------------------------------------------------------------
// Kernel 2: attention. Block = 4 waves = 2 q-tiles (16 rows) x 2 kv-halves.
// Swapped QK^T (lane owns q = lane&15). Packed-bit mask. Swizzled-V 1KB
// fragment loads. attn stores via wave-private XOR-swizzled LDS transpose
// (16 rows x 256B contiguous segments). ctx combine overlays ptile LDS.
// ---------------------------------------------------------------------------
__global__ __launch_bounds__(256, 8) void attn_kernel(
    const f16* __restrict__ qh, const f16* __restrict__ kh, const f16* __restrict__ vt,
    const u32* __restrict__ words,
    float* __restrict__ attn, float* __restrict__ ctx)
{
  const int bx = blockIdx.x;
  const int bh = bx >> 6;
  const int qp = bx & 63;
  const int wave = threadIdx.x >> 6;
  const int tile = wave >> 1;
  const int half = wave & 1;
  const int lane = threadIdx.x & 63;
  const int ln = lane & 15, hi = lane >> 4;
  const int b = bh >> 2, h = bh & 3;
  const int qrow = qp * 32 + tile * 16 + ln;
  const int kv0 = half * (S_LEN / 2);

  __shared__ f32x4 ptile[4][16][16];   // per-wave 4KB transpose tile
  __shared__ float sums[2][2][16];

  const f16* kbase = kh + (size_t)bh * S_LEN * DK;
  const f16* vbase = vt + (size_t)bh * DK * S_LEN;
  const u32* wrow = words + ((size_t)b * S_LEN + qrow) * (S_LEN / 32);

  const f16x8 qfrag = *(const f16x8*)(qh + ((size_t)bh * S_LEN + qrow) * DK + hi * 8);
  const f32x4 zero = {0.f, 0.f, 0.f, 0.f};

  // ---- pass 1: partial row sums of exp(scores), 64 kv per iter ----
  float sum = 0.f;
  {
    const f16* kp = kbase + (size_t)(kv0 + ln) * DK + hi * 8;
    for (int kv = kv0; kv < kv0 + S_LEN / 2; kv += 64) {
      u32x2 mw = *(const u32x2*)(wrow + (kv >> 5));
      f16x8 k0 = *(const f16x8*)(kp);
      f16x8 k1 = *(const f16x8*)(kp + 512);
      f16x8 k2 = *(const f16x8*)(kp + 1024);
      f16x8 k3 = *(const f16x8*)(kp + 1536);
      kp += 2048;
      f32x4 s0 = mfma_16x16x32(k0, qfrag, zero);
      f32x4 s1 = mfma_16x16x32(k1, qfrag, zero);
      f32x4 s2 = mfma_16x16x32(k2, qfrag, zero);
      f32x4 s3 = mfma_16x16x32(k3, qfrag, zero);
#pragma unroll
      for (int r = 0; r < 4; ++r) {
        float e0 = ((mw[0] >> (4 * hi + r)) & 1) ? 0.f : __expf(s0[r]);
        float e1 = ((mw[0] >> (16 + 4 * hi + r)) & 1) ? 0.f : __expf(s1[r]);
        float e2 = ((mw[1] >> (4 * hi + r)) & 1) ? 0.f : __expf(s2[r]);
        float e3 = ((mw[1] >> (16 + 4 * hi + r)) & 1) ? 0.f : __expf(s3[r]);
        sum += (e0 + e1) + (e2 + e3);
      }
    }
  }
  sum += __shfl_xor(sum, 16);
  sum += __shfl_xor(sum, 32);
  if (lane < 16) sums[tile][half][ln] = sum;
  __syncthreads();
  const float inv = 1.f / (sums[tile][0][ln] + sums[tile][1][ln]);

  // ---- pass 2: recompute, LDS-transposed attn store, partial PV ----
  f32x4 c0 = zero, c1 = zero;
  {
    const f16* kp = kbase + (size_t)(kv0 + ln) * DK + hi * 8;
    const f16* vp = vbase + (size_t)(kv0 >> 5) * 1024 + ln * 32 + hi * 8;
    for (int kv = kv0; kv < kv0 + S_LEN / 2; kv += 64) {
      u32x2 mw = *(const u32x2*)(wrow + (kv >> 5));
#pragma unroll
      for (int j = 0; j < 2; ++j) {
        f16x8 k0 = *(const f16x8*)(kp + j * 1024);
        f16x8 k1 = *(const f16x8*)(kp + j * 1024 + 512);
        f16x8 v0 = *(const f16x8*)(vp + j * 1024);
        f16x8 v1 = *(const f16x8*)(vp + j * 1024 + 512);
        f32x4 s0 = mfma_16x16x32(k0, qfrag, zero);
        f32x4 s1 = mfma_16x16x32(k1, qfrag, zero);
        u32 w = mw[j];
        f32x4 p0, p1;
#pragma unroll
        for (int r = 0; r < 4; ++r) {
          p0[r] = ((w >> (4 * hi + r)) & 1) ? 0.f : __expf(s0[r]) * inv;
          p1[r] = ((w >> (16 + 4 * hi + r)) & 1) ? 0.f : __expf(s1[r]) * inv;
        }
        f16x8 pf;
#pragma unroll
        for (int r = 0; r < 4; ++r) { pf[r] = (f16)p0[r]; pf[r + 4] = (f16)p1[r]; }
        c0 = mfma_16x16x32(v0, pf, c0);
        c1 = mfma_16x16x32(v1, pf, c1);
        // stage into wave-private LDS (col-unit XOR swizzle; 2-way banks)
        ptile[wave][ln][(j * 8 + hi) ^ (ln & 7)] = p0;
        ptile[wave][ln][(j * 8 + 4 + hi) ^ (ln & 7)] = p1;
      }
      kp += 2048;
      vp += 2048;
      // transpose-store: 16 rows x 64 floats, 256B contiguous per row
#pragma unroll
      for (int s = 0; s < 4; ++s) {
        int row = s * 4 + hi;
        f32x4 val = ptile[wave][row][ln ^ (row & 7)];
        int qr = qp * 32 + tile * 16 + row;
        float* dst = attn + ((size_t)bh * S_LEN + qr) * S_LEN + kv + ln * 4;
        *(f32x4*)dst = val;
      }
    }
  }

  // ---- combine the two kv-half partial PVs (overlay ptile of half==1 wave) ----
  if (half == 1) {
    float* cb = (float*)&ptile[tile * 2 + 1][0][0];
#pragma unroll
    for (int r = 0; r < 4; ++r) {
      cb[ln * 32 + hi * 4 + r] = c0[r];
      cb[ln * 32 + 16 + hi * 4 + r] = c1[r];
    }
  }
  __syncthreads();
  if (half == 0) {
    const float* cb = (const float*)&ptile[tile * 2 + 1][0][0];
#pragma unroll
    for (int r = 0; r < 4; ++r) {
      c0[r] += cb[ln * 32 + hi * 4 + r];
      c1[r] += cb[ln * 32 + 16 + hi * 4 + r];
    }
    float* crow = ctx + ((size_t)b * S_LEN + qrow) * DM + h * DK;
    *(f32x4*)(crow + hi * 4) = c0;
    *(f32x4*)(crow + 16 + hi * 4) = c1;
  }
}

// ---------------------------------------------------------------------------
// Kernel 3: out = LayerNorm(ctx @ wo + bo + residual(Q)) * gamma + beta
// ---------------------------------------------------------------------------
__global__ __launch_bounds__(256) void out_ln_kernel(
    const float* __restrict__ ctx, const float* __restrict__ Qin,
    const float* __restrict__ wo, const float* __restrict__ bo,
    const float* __restrict__ gamma, const float* __restrict__ beta,
    float* __restrict__ out)
{
  __shared__ float xt[16][128];
  __shared__ float yt[16][128];
  const int t = threadIdx.x;
  const int row0 = blockIdx.x * 16;

  const f32x4* src = (const f32x4*)(ctx + (size_t)row0 * DM);
  f32x4* dst4 = (f32x4*)(&xt[0][0]);
  dst4[t] = src[t];
  dst4[t + 256] = src[t + 256];
  __syncthreads();

  const int j = t & 127;
  const int rg = t >> 7;
  float acc[8];
#pragma unroll
  for (int r = 0; r < 8; ++r) acc[r] = 0.f;
  for (int k = 0; k < 128; ++k) {
    float wkj = wo[k * 128 + j];
#pragma unroll
    for (int r = 0; r < 8; ++r) acc[r] += xt[rg * 8 + r][k] * wkj;
  }
  const float bb = bo[j];
#pragma unroll
  for (int r = 0; r < 8; ++r) {
    int row = row0 + rg * 8 + r;
    yt[rg * 8 + r][j] = acc[r] + bb + Qin[(size_t)row * DM + j];
  }
  __syncthreads();

  const int wv = t >> 6, lnid = t & 63;
#pragma unroll
  for (int r = 0; r < 4; ++r) {
    int row = wv * 4 + r;
    float a = yt[row][lnid];
    float b2 = yt[row][lnid + 64];
    float s = a + b2, sq = a * a + b2 * b2;
#pragma unroll
    for (int off = 32; off >= 1; off >>= 1) {
      s += __shfl_xor(s, off);
      sq += __shfl_xor(sq, off);
    }
    float mu = s * (1.f / 128.f);
    float var = sq * (1.f / 128.f) - mu * mu;
    float rstd = rsqrtf(var + 1e-5f);
    size_t orow = (size_t)(row0 + row) * DM;
    out[orow + lnid] = (a - mu) * rstd * gamma[lnid] + beta[lnid];
    out[orow + lnid + 64] = (b2 - mu) * rstd * gamma[lnid + 64] + beta[lnid + 64];
  }
}

// ---------------------------------------------------------------------------
extern "C" void kernel_launch(void* const* d_in, const int* in_sizes, int n_in,
                              void* d_out, int out_size, void* d_ws, size_t ws_size,
                              hipStream_t stream) {
  const float* Q    = (const float*)d_in[0];
  const float* K    = (const float*)d_in[1];
  const float* V    = (const float*)d_in[2];
  const unsigned char* mask = (const unsigned char*)d_in[3];
  const float* wq   = (const float*)d_in[4];
  const float* bq   = (const float*)d_in[5];
  const float* wk   = (const float*)d_in[6];
  const float* bk   = (const float*)d_in[7];
  const float* wv   = (const float*)d_in[8];
  const float* bv   = (const float*)d_in[9];
  const float* wo   = (const float*)d_in[10];
  const float* bo   = (const float*)d_in[11];
  const float* gamma= (const float*)d_in[12];
  const float* beta = (const float*)d_in[13];

  const size_t HEAD_ELEMS = (size_t)NB * NH * S_LEN * DK;  // 2,097,152

  f16* qh = (f16*)d_ws;
  f16* kh = qh + HEAD_ELEMS;
  f16* vt = kh + HEAD_ELEMS;
  float* ctx = (float*)(vt + HEAD_ELEMS);                  // 8 MB fp32
  u32* words = (u32*)(ctx + (size_t)NB * S_LEN * DM);      // 4 MB packed mask

  float* out  = (float*)d_out;                             // [8,2048,128]
  float* attn = out + (size_t)NB * S_LEN * DM;             // [8,4,2048,2048]

  pack_mask_kernel<<<8192, 256, 0, stream>>>(mask, words);
  proj_kernel<<<dim3(1024, 3), 256, 0, stream>>>(Q, K, V, wq, bq, wk, bk, wv, bv, qh, kh, vt);
  attn_kernel<<<2048, 256, 0, stream>>>(qh, kh, vt, words, attn, ctx);
  out_ln_kernel<<<1024, 256, 0, stream>>>(ctx, Q, wo, bo, gamma, beta, out);
}

// Round 4
// 200.175 us; speedup vs baseline: 1.7568x; 1.6570x over previous
//
#include <hip/hip_runtime.h>

typedef _Float16 f16;
typedef __attribute__((ext_vector_type(8))) _Float16 f16x8;
typedef __attribute__((ext_vector_type(4))) _Float16 f16x4;
typedef __attribute__((ext_vector_type(4))) float f32x4;
typedef unsigned int u32;
typedef __attribute__((ext_vector_type(2))) unsigned int u32x2;
typedef __attribute__((ext_vector_type(4))) unsigned int u32x4;

#define S_LEN 2048
#define NB 8
#define NH 4
#define DM 128
#define DK 32

static __device__ __forceinline__ f32x4 mfma_16x16x32(f16x8 a, f16x8 b, f32x4 c) {
  return __builtin_amdgcn_mfma_f32_16x16x32_f16(a, b, c, 0, 0, 0);
}

// ---------------------------------------------------------------------------
// Kernel 0: pack bool mask (uint8) into bit-words. word w bit j = mask[32w+j].
// ---------------------------------------------------------------------------
__global__ __launch_bounds__(256) void pack_mask_kernel(
    const unsigned char* __restrict__ mask, u32* __restrict__ words)
{
  const int tid = blockIdx.x * 256 + threadIdx.x;
  u32x4 v = *(const u32x4*)(mask + (size_t)tid * 16);
  u32 bits = 0;
#pragma unroll
  for (int i = 0; i < 4; ++i) {
    u32 u = v[i];
#pragma unroll
    for (int k = 0; k < 4; ++k)
      bits |= (((u >> (8 * k)) & 0xffu) ? 1u : 0u) << (4 * i + k);
  }
  u32 other = __shfl_xor(bits, 1);
  if ((threadIdx.x & 1) == 0) words[tid >> 1] = bits | (other << 16);
}

// ---------------------------------------------------------------------------
// Kernel 1: fused q/k/v projections.
//   mode 0: qh[bh][s][dk] = (Q@wq + bq) * (1/sqrt(32))   (fp16)
//   mode 1: kh[bh][s][dk] = (K@wk + bk)                  (fp16)
//   mode 2: vt swizzled tiles: per bh, 32-kv tile t, layout [dv(32)][hi(4)][8]
// ---------------------------------------------------------------------------
__global__ __launch_bounds__(256) void proj_kernel(
    const float* __restrict__ Qx, const float* __restrict__ Kx, const float* __restrict__ Vx,
    const float* __restrict__ wq, const float* __restrict__ bq,
    const float* __restrict__ wk, const float* __restrict__ bk,
    const float* __restrict__ wv, const float* __restrict__ bv,
    f16* __restrict__ qh, f16* __restrict__ kh, f16* __restrict__ vt)
{
  const int mode = blockIdx.y;
  const float* X = (mode == 0) ? Qx : (mode == 1) ? Kx : Vx;
  const float* W = (mode == 0) ? wq : (mode == 1) ? wk : wv;
  const float* Bp = (mode == 0) ? bq : (mode == 1) ? bk : bv;

  __shared__ float xt[16][128];
  const int t = threadIdx.x;
  const int row0 = blockIdx.x * 16;

  const f32x4* src = (const f32x4*)(X + (size_t)row0 * DM);
  f32x4* dst4 = (f32x4*)(&xt[0][0]);
  dst4[t] = src[t];
  dst4[t + 256] = src[t + 256];
  __syncthreads();

  const int j = t & 127;
  const int rg = t >> 7;
  float acc[8];
#pragma unroll
  for (int r = 0; r < 8; ++r) acc[r] = 0.f;
  for (int k = 0; k < 128; ++k) {
    float wkj = W[k * 128 + j];
#pragma unroll
    for (int r = 0; r < 8; ++r) acc[r] += xt[rg * 8 + r][k] * wkj;
  }
  const float bb = Bp[j];
  const int hh = j >> 5, dd = j & 31;

  if (mode < 2) {
    const float scale = (mode == 0) ? 0.17677669529663687f : 1.0f;  // 1/sqrt(32)
    f16* outp = (mode == 0) ? qh : kh;
#pragma unroll
    for (int r = 0; r < 8; ++r) {
      int row = row0 + rg * 8 + r;
      int b = row >> 11, s = row & (S_LEN - 1);
      outp[((size_t)(b * NH + hh) * S_LEN + s) * DK + dd] = (f16)((acc[r] + bb) * scale);
    }
  } else {
    int b = row0 >> 11;
    int sA = (row0 & (S_LEN - 1)) + rg * 8;
    f16* base = vt + (size_t)(b * NH + hh) * DK * S_LEN;
    int t4 = sA >> 5;
    int u0 = sA & 31;
    int half = u0 >> 4;
    int hi4 = (u0 >> 2) & 3;
    f16* p = base + (size_t)t4 * 1024 + dd * 32 + half * 4;
    f16x4 lo, hi8;
#pragma unroll
    for (int r = 0; r < 4; ++r) lo[r] = (f16)(acc[r] + bb);
#pragma unroll
    for (int r = 0; r < 4; ++r) hi8[r] = (f16)(acc[r + 4] + bb);
    *(f16x4*)(p + hi4 * 8) = lo;
    *(f16x4*)(p + (hi4 + 1) * 8) = hi8;
  }
}

// ---------------------------------------------------------------------------
// Kernel 2: attention, register-software-pipelined.
// Block = 4 waves = 2 q-tiles x 2 kv-halves. LB(256,4) -> 128 VGPR budget so
// the next iteration's K+mask (and current V early) stay in flight while the
// current iteration computes. Everything else as round 3.
// ---------------------------------------------------------------------------
__global__ __launch_bounds__(256, 4) void attn_kernel(
    const f16* __restrict__ qh, const f16* __restrict__ kh, const f16* __restrict__ vt,
    const u32* __restrict__ words,
    float* __restrict__ attn, float* __restrict__ ctx)
{
  const int bx = blockIdx.x;
  const int bh = bx >> 6;
  const int qp = bx & 63;
  const int wave = threadIdx.x >> 6;
  const int tile = wave >> 1;
  const int half = wave & 1;
  const int lane = threadIdx.x & 63;
  const int ln = lane & 15, hi = lane >> 4;
  const int b = bh >> 2, h = bh & 3;
  const int qrow = qp * 32 + tile * 16 + ln;
  const int kv0 = half * (S_LEN / 2);

  __shared__ f32x4 ptile[4][16][16];
  __shared__ float sums[2][2][16];

  const f16* kbase = kh + (size_t)bh * S_LEN * DK;
  const f16* vbase = vt + (size_t)bh * DK * S_LEN;
  const u32* wrow = words + ((size_t)b * S_LEN + qrow) * (S_LEN / 32);

  const f16x8 qfrag = *(const f16x8*)(qh + ((size_t)bh * S_LEN + qrow) * DK + hi * 8);
  const f32x4 zero = {0.f, 0.f, 0.f, 0.f};

  // ---- pass 1: 128 kv per iter, depth-1 register prefetch of K + mask ----
  float sum = 0.f;
  {
    const f16* kp = kbase + (size_t)(kv0 + ln) * DK + hi * 8;
    const u32* mp = wrow + (kv0 >> 5);
    f16x8 k0 = *(const f16x8*)(kp);
    f16x8 k1 = *(const f16x8*)(kp + 512);
    f16x8 k2 = *(const f16x8*)(kp + 1024);
    f16x8 k3 = *(const f16x8*)(kp + 1536);
    f16x8 k4 = *(const f16x8*)(kp + 2048);
    f16x8 k5 = *(const f16x8*)(kp + 2560);
    f16x8 k6 = *(const f16x8*)(kp + 3072);
    f16x8 k7 = *(const f16x8*)(kp + 3584);
    u32x4 mw = *(const u32x4*)mp;
    for (int it = 0; it < 8; ++it) {
      f16x8 n0, n1, n2, n3, n4, n5, n6, n7;
      u32x4 nm;
      if (it < 7) {
        n0 = *(const f16x8*)(kp + 4096);
        n1 = *(const f16x8*)(kp + 4608);
        n2 = *(const f16x8*)(kp + 5120);
        n3 = *(const f16x8*)(kp + 5632);
        n4 = *(const f16x8*)(kp + 6144);
        n5 = *(const f16x8*)(kp + 6656);
        n6 = *(const f16x8*)(kp + 7168);
        n7 = *(const f16x8*)(kp + 7680);
        nm = *(const u32x4*)(mp + 4);
      }
      f32x4 s0 = mfma_16x16x32(k0, qfrag, zero);
      f32x4 s1 = mfma_16x16x32(k1, qfrag, zero);
      f32x4 s2 = mfma_16x16x32(k2, qfrag, zero);
      f32x4 s3 = mfma_16x16x32(k3, qfrag, zero);
      f32x4 s4 = mfma_16x16x32(k4, qfrag, zero);
      f32x4 s5 = mfma_16x16x32(k5, qfrag, zero);
      f32x4 s6 = mfma_16x16x32(k6, qfrag, zero);
      f32x4 s7 = mfma_16x16x32(k7, qfrag, zero);
#pragma unroll
      for (int r = 0; r < 4; ++r) {
        float e0 = ((mw[0] >> (4 * hi + r)) & 1) ? 0.f : __expf(s0[r]);
        float e1 = ((mw[0] >> (16 + 4 * hi + r)) & 1) ? 0.f : __expf(s1[r]);
        float e2 = ((mw[1] >> (4 * hi + r)) & 1) ? 0.f : __expf(s2[r]);
        float e3 = ((mw[1] >> (16 + 4 * hi + r)) & 1) ? 0.f : __expf(s3[r]);
        float e4 = ((mw[2] >> (4 * hi + r)) & 1) ? 0.f : __expf(s4[r]);
        float e5 = ((mw[2] >> (16 + 4 * hi + r)) & 1) ? 0.f : __expf(s5[r]);
        float e6 = ((mw[3] >> (4 * hi + r)) & 1) ? 0.f : __expf(s6[r]);
        float e7 = ((mw[3] >> (16 + 4 * hi + r)) & 1) ? 0.f : __expf(s7[r]);
        sum += ((e0 + e1) + (e2 + e3)) + ((e4 + e5) + (e6 + e7));
      }
      k0 = n0; k1 = n1; k2 = n2; k3 = n3;
      k4 = n4; k5 = n5; k6 = n6; k7 = n7;
      mw = nm;
      kp += 4096;
      mp += 4;
    }
  }
  sum += __shfl_xor(sum, 16);
  sum += __shfl_xor(sum, 32);
  if (lane < 16) sums[tile][half][ln] = sum;
  __syncthreads();
  const float inv = 1.f / (sums[tile][0][ln] + sums[tile][1][ln]);

  // ---- pass 2: 64 kv per iter; current-V issued early, next K+mask prefetch ----
  f32x4 c0 = zero, c1 = zero;
  {
    const f16* kp = kbase + (size_t)(kv0 + ln) * DK + hi * 8;
    const f16* vp = vbase + (size_t)(kv0 >> 5) * 1024 + ln * 32 + hi * 8;
    const u32* mp = wrow + (kv0 >> 5);
    f16x8 k0 = *(const f16x8*)(kp);
    f16x8 k1 = *(const f16x8*)(kp + 512);
    f16x8 k2 = *(const f16x8*)(kp + 1024);
    f16x8 k3 = *(const f16x8*)(kp + 1536);
    u32x2 mw = *(const u32x2*)mp;
    for (int it = 0; it < 16; ++it) {
      const int kv = kv0 + it * 64;
      // current V — issued before compute so PV's wait is covered by QK+exp
      f16x8 v0 = *(const f16x8*)(vp);
      f16x8 v1 = *(const f16x8*)(vp + 512);
      f16x8 v2 = *(const f16x8*)(vp + 1024);
      f16x8 v3 = *(const f16x8*)(vp + 1536);
      // next iteration's K + mask
      f16x8 n0, n1, n2, n3;
      u32x2 nm;
      if (it < 15) {
        n0 = *(const f16x8*)(kp + 2048);
        n1 = *(const f16x8*)(kp + 2560);
        n2 = *(const f16x8*)(kp + 3072);
        n3 = *(const f16x8*)(kp + 3584);
        nm = *(const u32x2*)(mp + 2);
      }
      // ---- j = 0 : kv .. kv+31 ----
      f32x4 s0 = mfma_16x16x32(k0, qfrag, zero);
      f32x4 s1 = mfma_16x16x32(k1, qfrag, zero);
      f32x4 p0, p1;
#pragma unroll
      for (int r = 0; r < 4; ++r) {
        p0[r] = ((mw[0] >> (4 * hi + r)) & 1) ? 0.f : __expf(s0[r]) * inv;
        p1[r] = ((mw[0] >> (16 + 4 * hi + r)) & 1) ? 0.f : __expf(s1[r]) * inv;
      }
      f16x8 pfA;
#pragma unroll
      for (int r = 0; r < 4; ++r) { pfA[r] = (f16)p0[r]; pfA[r + 4] = (f16)p1[r]; }
      c0 = mfma_16x16x32(v0, pfA, c0);
      c1 = mfma_16x16x32(v1, pfA, c1);
      ptile[wave][ln][(0 + hi) ^ (ln & 7)] = p0;
      ptile[wave][ln][(4 + hi) ^ (ln & 7)] = p1;
      // ---- j = 1 : kv+32 .. kv+63 ----
      f32x4 s2 = mfma_16x16x32(k2, qfrag, zero);
      f32x4 s3 = mfma_16x16x32(k3, qfrag, zero);
      f32x4 p2, p3;
#pragma unroll
      for (int r = 0; r < 4; ++r) {
        p2[r] = ((mw[1] >> (4 * hi + r)) & 1) ? 0.f : __expf(s2[r]) * inv;
        p3[r] = ((mw[1] >> (16 + 4 * hi + r)) & 1) ? 0.f : __expf(s3[r]) * inv;
      }
      f16x8 pfB;
#pragma unroll
      for (int r = 0; r < 4; ++r) { pfB[r] = (f16)p2[r]; pfB[r + 4] = (f16)p3[r]; }
      c0 = mfma_16x16x32(v2, pfB, c0);
      c1 = mfma_16x16x32(v3, pfB, c1);
      ptile[wave][ln][(8 + hi) ^ (ln & 7)] = p2;
      ptile[wave][ln][(12 + hi) ^ (ln & 7)] = p3;
      // ---- transpose-store 16 rows x 256B contiguous (nontemporal) ----
#pragma unroll
      for (int s = 0; s < 4; ++s) {
        int row = s * 4 + hi;
        f32x4 val = ptile[wave][row][ln ^ (row & 7)];
        int qr = qp * 32 + tile * 16 + row;
        float* dst = attn + ((size_t)bh * S_LEN + qr) * S_LEN + kv + ln * 4;
        __builtin_nontemporal_store(val, (f32x4*)dst);
      }
      k0 = n0; k1 = n1; k2 = n2; k3 = n3;
      mw = nm;
      kp += 2048;
      vp += 2048;
      mp += 2;
    }
  }

  // ---- combine the two kv-half partial PVs (overlay ptile of half==1 wave) ----
  if (half == 1) {
    float* cb = (float*)&ptile[tile * 2 + 1][0][0];
#pragma unroll
    for (int r = 0; r < 4; ++r) {
      cb[ln * 32 + hi * 4 + r] = c0[r];
      cb[ln * 32 + 16 + hi * 4 + r] = c1[r];
    }
  }
  __syncthreads();
  if (half == 0) {
    const float* cb = (const float*)&ptile[tile * 2 + 1][0][0];
#pragma unroll
    for (int r = 0; r < 4; ++r) {
      c0[r] += cb[ln * 32 + hi * 4 + r];
      c1[r] += cb[ln * 32 + 16 + hi * 4 + r];
    }
    float* crow = ctx + ((size_t)b * S_LEN + qrow) * DM + h * DK;
    *(f32x4*)(crow + hi * 4) = c0;
    *(f32x4*)(crow + 16 + hi * 4) = c1;
  }
}

// ---------------------------------------------------------------------------
// Kernel 3: out = LayerNorm(ctx @ wo + bo + residual(Q)) * gamma + beta
// ---------------------------------------------------------------------------
__global__ __launch_bounds__(256) void out_ln_kernel(
    const float* __restrict__ ctx, const float* __restrict__ Qin,
    const float* __restrict__ wo, const float* __restrict__ bo,
    const float* __restrict__ gamma, const float* __restrict__ beta,
    float* __restrict__ out)
{
  __shared__ float xt[16][128];
  __shared__ float yt[16][128];
  const int t = threadIdx.x;
  const int row0 = blockIdx.x * 16;

  const f32x4* src = (const f32x4*)(ctx + (size_t)row0 * DM);
  f32x4* dst4 = (f32x4*)(&xt[0][0]);
  dst4[t] = src[t];
  dst4[t + 256] = src[t + 256];
  __syncthreads();

  const int j = t & 127;
  const int rg = t >> 7;
  float acc[8];
#pragma unroll
  for (int r = 0; r < 8; ++r) acc[r] = 0.f;
  for (int k = 0; k < 128; ++k) {
    float wkj = wo[k * 128 + j];
#pragma unroll
    for (int r = 0; r < 8; ++r) acc[r] += xt[rg * 8 + r][k] * wkj;
  }
  const float bb = bo[j];
#pragma unroll
  for (int r = 0; r < 8; ++r) {
    int row = row0 + rg * 8 + r;
    yt[rg * 8 + r][j] = acc[r] + bb + Qin[(size_t)row * DM + j];
  }
  __syncthreads();

  const int wv = t >> 6, lnid = t & 63;
#pragma unroll
  for (int r = 0; r < 4; ++r) {
    int row = wv * 4 + r;
    float a = yt[row][lnid];
    float b2 = yt[row][lnid + 64];
    float s = a + b2, sq = a * a + b2 * b2;
#pragma unroll
    for (int off = 32; off >= 1; off >>= 1) {
      s += __shfl_xor(s, off);
      sq += __shfl_xor(sq, off);
    }
    float mu = s * (1.f / 128.f);
    float var = sq * (1.f / 128.f) - mu * mu;
    float rstd = rsqrtf(var + 1e-5f);
    size_t orow = (size_t)(row0 + row) * DM;
    out[orow + lnid] = (a - mu) * rstd * gamma[lnid] + beta[lnid];
    out[orow + lnid + 64] = (b2 - mu) * rstd * gamma[lnid + 64] + beta[lnid + 64];
  }
}

// ---------------------------------------------------------------------------
extern "C" void kernel_launch(void* const* d_in, const int* in_sizes, int n_in,
                              void* d_out, int out_size, void* d_ws, size_t ws_size,
                              hipStream_t stream) {
  const float* Q    = (const float*)d_in[0];
  const float* K    = (const float*)d_in[1];
  const float* V    = (const float*)d_in[2];
  const unsigned char* mask = (const unsigned char*)d_in[3];
  const float* wq   = (const float*)d_in[4];
  const float* bq   = (const float*)d_in[5];
  const float* wk   = (const float*)d_in[6];
  const float* bk   = (const float*)d_in[7];
  const float* wv   = (const float*)d_in[8];
  const float* bv   = (const float*)d_in[9];
  const float* wo   = (const float*)d_in[10];
  const float* bo   = (const float*)d_in[11];
  const float* gamma= (const float*)d_in[12];
  const float* beta = (const float*)d_in[13];

  const size_t HEAD_ELEMS = (size_t)NB * NH * S_LEN * DK;  // 2,097,152

  f16* qh = (f16*)d_ws;
  f16* kh = qh + HEAD_ELEMS;
  f16* vt = kh + HEAD_ELEMS;
  float* ctx = (float*)(vt + HEAD_ELEMS);                  // 8 MB fp32
  u32* words = (u32*)(ctx + (size_t)NB * S_LEN * DM);      // 4 MB packed mask

  float* out  = (float*)d_out;                             // [8,2048,128]
  float* attn = out + (size_t)NB * S_LEN * DM;             // [8,4,2048,2048]

  pack_mask_kernel<<<8192, 256, 0, stream>>>(mask, words);
  proj_kernel<<<dim3(1024, 3), 256, 0, stream>>>(Q, K, V, wq, bq, wk, bk, wv, bv, qh, kh, vt);
  attn_kernel<<<2048, 256, 0, stream>>>(qh, kh, vt, words, attn, ctx);
  out_ln_kernel<<<1024, 256, 0, stream>>>(ctx, Q, wo, bo, gamma, beta, out);
}